// Round 5
// baseline (403.400 us; speedup 1.0000x reference)
//
#include <hip/hip_runtime.h>
#include <hip/hip_bf16.h>

typedef unsigned short u16;
typedef float  f32x4  __attribute__((ext_vector_type(4)));
typedef __bf16 bf16x8 __attribute__((ext_vector_type(8)));
typedef unsigned short u16x8 __attribute__((ext_vector_type(8)));
typedef unsigned short u16x4 __attribute__((ext_vector_type(4)));

__device__ __forceinline__ u16 f2bfu(float f) {
    __hip_bfloat16 h = __float2bfloat16(f);
    return __builtin_bit_cast(unsigned short, h);
}

constexpr int kHW = 196;   // 14*14
constexpr int kKC = 25;    // ceil(196/8) k-chunks
constexpr int kLC = 25;    // ceil(196/8) l-chunks
constexpr int kChunks = kKC * kLC;  // 625 per batch

// ---------------- fp32 64x64 tile transpose ----------------
__global__ void k_tr_f32(const float* __restrict__ in, float* __restrict__ out,
                         int R, int Ccols) {
    __shared__ float t[64][65];
    int c0 = blockIdx.x * 64, r0 = blockIdx.y * 64;
    int lc = threadIdx.x & 63, lg = threadIdx.x >> 6;
#pragma unroll
    for (int rr = 0; rr < 16; ++rr) {
        int r = lg * 16 + rr;
        t[r][lc] = in[(r0 + r) * Ccols + c0 + lc];
    }
    __syncthreads();
#pragma unroll
    for (int rr = 0; rr < 16; ++rr) {
        int r = lg * 16 + rr;
        out[(c0 + r) * R + r0 + lc] = t[lc][r];
    }
}

// ---------------- fp32 -> bf16 transpose ----------------
__global__ void k_tr_bf16(const float* __restrict__ in, u16* __restrict__ out,
                          int R, int Ccols) {
    __shared__ float t[64][65];
    int c0 = blockIdx.x * 64, r0 = blockIdx.y * 64;
    int lc = threadIdx.x & 63, lg = threadIdx.x >> 6;
#pragma unroll
    for (int rr = 0; rr < 16; ++rr) {
        int r = lg * 16 + rr;
        t[r][lc] = in[(r0 + r) * Ccols + c0 + lc];
    }
    __syncthreads();
#pragma unroll
    for (int rr = 0; rr < 16; ++rr) {
        int r = lg * 16 + rr;
        out[(c0 + r) * R + r0 + lc] = f2bfu(t[lc][r]);
    }
}

// ---------------- fused xf + al/ak: grid (25, 8), 512 thr ----------------
__global__ __launch_bounds__(512)
void k_xa(const float* __restrict__ im, const float* __restrict__ pwT,
          const float* __restrict__ pb, const float* __restrict__ w1,
          float* __restrict__ al, float* __restrict__ ak) {
    __shared__ float sm[512 * 8];
    __shared__ float smx[256 * 8];
    const int tid = threadIdx.x;
    const int b = blockIdx.y;
    const int p0 = blockIdx.x * 8;
#pragma unroll
    for (int it = 0; it < 8; ++it) {
        int idx = it * 512 + tid;
        int i = idx >> 3, pi = idx & 7;
        int p = p0 + pi;
        sm[idx] = (p < kHW) ? im[(b * 512 + i) * kHW + p] : 0.f;
    }
    __syncthreads();
    const int c = tid & 255;
    const int half = tid >> 8;
    float acc[8] = {};
    {
        const int ibase = half * 256;
        for (int k = 0; k < 256; ++k) {
            int i = ibase + k;
            float w = pwT[(i << 8) + c];
            f32x4 x0 = *(const f32x4*)&sm[i * 8];
            f32x4 x1 = *(const f32x4*)&sm[i * 8 + 4];
#pragma unroll
            for (int j = 0; j < 4; ++j) { acc[j] += x0[j] * w; acc[4 + j] += x1[j] * w; }
        }
    }
    __syncthreads();
    if (half) {
#pragma unroll
        for (int pi = 0; pi < 8; ++pi) sm[c * 8 + pi] = acc[pi];
    }
    __syncthreads();
    if (!half) {
        float bias = pb[c];
#pragma unroll
        for (int pi = 0; pi < 8; ++pi) smx[c * 8 + pi] = acc[pi] + sm[c * 8 + pi] + bias;
    }
    __syncthreads();
    float a2[8] = {};
    const float* wb = w1 + half * 256 * 256;
    for (int k = 0; k < 256; ++k) {
        float w = wb[(k << 8) + c];
        f32x4 x0 = *(const f32x4*)&smx[k * 8];
        f32x4 x1 = *(const f32x4*)&smx[k * 8 + 4];
#pragma unroll
        for (int j = 0; j < 4; ++j) { a2[j] += x0[j] * w; a2[4 + j] += x1[j] * w; }
    }
    float* dst = half ? ak : al;
#pragma unroll
    for (int pi = 0; pi < 8; ++pi) {
        int p = p0 + pi;
        if (p < kHW) dst[((b * kHW + p) << 8) + c] = a2[pi];
    }
}

// ---------------- main fused pair kernel v4: fn=8/fm=2, pipelined ----------------
// grid (25 lc, 25 kc, 8 b), block 256 = 4 waves: wm(2 pair-halves) x wn(2 ch-halves).
// Wave tile: 128 ch x 32 pairs -> acc[8][2] f32x4 = 64 AGPR; ratio 8 MFMA per ds_read.
// Both GEMM K-loops fully unrolled with 2-deep double-buffered prefetch.
__global__ __launch_bounds__(256, 2)
void k_main4(const float* __restrict__ ak, const float* __restrict__ al,
             const float* __restrict__ b1, const u16* __restrict__ w2t,
             const float* __restrict__ b2, const u16* __restrict__ w3t,
             const float* __restrict__ b3, float* __restrict__ part) {
    __shared__ u16 smem[64 * 256];  // 32 KB: h1, then h2 in-place
    const int tid = threadIdx.x;
    const int lc = blockIdx.x, kc = blockIdx.y, b = blockIdx.z;
    const int k0 = kc * 8, l0 = lc * 8;

    // ---- stage h1 = relu(ak[k] + al[l] + b1) -> bf16 LDS [pair][ch], swizzled ----
#pragma unroll
    for (int it = 0; it < 8; ++it) {
        int chunk = it * 256 + tid;
        int row = chunk >> 5;
        int cc = chunk & 31;
        int ki = k0 + (row >> 3); if (ki > 195) ki = 195;
        int li = l0 + (row & 7);  if (li > 195) li = 195;
        const float* akp = ak + ((b * kHW + ki) << 8) + (cc << 3);
        const float* alp = al + ((b * kHW + li) << 8) + (cc << 3);
        const float* b1p = b1 + (cc << 3);
        f32x4 k0v = *(const f32x4*)akp;
        f32x4 k1v = *(const f32x4*)(akp + 4);
        f32x4 l0v = *(const f32x4*)alp;
        f32x4 l1v = *(const f32x4*)(alp + 4);
        f32x4 c0v = *(const f32x4*)b1p;
        f32x4 c1v = *(const f32x4*)(b1p + 4);
        u16x8 v;
#pragma unroll
        for (int j = 0; j < 4; ++j) {
            v[j]     = f2bfu(fmaxf(k0v[j] + l0v[j] + c0v[j], 0.f));
            v[4 + j] = f2bfu(fmaxf(k1v[j] + l1v[j] + c1v[j], 0.f));
        }
        int byte = (row << 9) + (cc << 4);
        byte ^= (row & 7) << 4;
        *(u16x8*)((char*)smem + byte) = v;
    }
    __syncthreads();

    const int lane = tid & 63;
    const int wid = tid >> 6;
    const int wm = wid >> 1;   // pair half (32 pairs)
    const int wn = wid & 1;    // channel half (128 ch)
    const int l15 = lane & 15;
    const int kg = lane >> 4;

    f32x4 acc[8][2];
    bf16x8 wfA[8], wfB[8], hfA[2], hfB[2];

#define LOADW(DST, WP, KK)                                                     \
    {                                                                          \
        int kb_ = (KK) * 32 + kg * 8;                                          \
        _Pragma("unroll")                                                      \
        for (int f_ = 0; f_ < 8; ++f_)                                         \
            DST[f_] = __builtin_bit_cast(                                      \
                bf16x8, *(const u16x8*)((WP) + (f_ << 12) + kb_));             \
    }
#define LOADH(DST, KK)                                                         \
    {                                                                          \
        int kb_ = (KK) * 32 + kg * 8;                                          \
        _Pragma("unroll")                                                      \
        for (int m_ = 0; m_ < 2; ++m_) {                                       \
            int row_ = wm * 32 + m_ * 16 + l15;                                \
            int byte_ = (row_ << 9) + (kb_ << 1);                              \
            byte_ ^= (row_ & 7) << 4;                                          \
            DST[m_] = __builtin_bit_cast(                                      \
                bf16x8, *(const u16x8*)((const char*)smem + byte_));           \
        }                                                                      \
    }
#define MFMA_STEP(WF, HF)                                                      \
    {                                                                          \
        _Pragma("unroll")                                                      \
        for (int f_ = 0; f_ < 8; ++f_)                                         \
            _Pragma("unroll")                                                  \
            for (int m_ = 0; m_ < 2; ++m_)                                     \
                acc[f_][m_] = __builtin_amdgcn_mfma_f32_16x16x32_bf16(         \
                    WF[f_], HF[m_], acc[f_][m_], 0, 0, 0);                     \
    }
#define GEMM_PIPE(WP)                                                          \
    LOADW(wfA, WP, 0) LOADH(hfA, 0)                                            \
    LOADW(wfB, WP, 1) LOADH(hfB, 1)                                            \
    MFMA_STEP(wfA, hfA)                                                        \
    LOADW(wfA, WP, 2) LOADH(hfA, 2)                                            \
    MFMA_STEP(wfB, hfB)                                                        \
    LOADW(wfB, WP, 3) LOADH(hfB, 3)                                            \
    MFMA_STEP(wfA, hfA)                                                        \
    LOADW(wfA, WP, 4) LOADH(hfA, 4)                                            \
    MFMA_STEP(wfB, hfB)                                                        \
    LOADW(wfB, WP, 5) LOADH(hfB, 5)                                            \
    MFMA_STEP(wfA, hfA)                                                        \
    LOADW(wfA, WP, 6) LOADH(hfA, 6)                                            \
    MFMA_STEP(wfB, hfB)                                                        \
    LOADW(wfB, WP, 7) LOADH(hfB, 7)                                            \
    MFMA_STEP(wfA, hfA)                                                        \
    MFMA_STEP(wfB, hfB)

    // ---- GEMM1: h2^T = w2 x h1^T ----
#pragma unroll
    for (int f = 0; f < 8; ++f)
#pragma unroll
        for (int m = 0; m < 2; ++m) acc[f][m] = f32x4{0.f, 0.f, 0.f, 0.f};
    {
        const u16* wp = w2t + ((wn * 128 + l15) << 8);
        GEMM_PIPE(wp)
    }
    __syncthreads();

    // ---- epilogue: h2 = relu(D1 + b2) -> bf16 LDS, packed 8B writes ----
#pragma unroll
    for (int f = 0; f < 8; ++f) {
        f32x4 b2v = *(const f32x4*)(b2 + wn * 128 + f * 16 + kg * 4);
#pragma unroll
        for (int m = 0; m < 2; ++m) {
            int prow = wm * 32 + m * 16 + l15;
            u16x4 pv;
#pragma unroll
            for (int r = 0; r < 4; ++r)
                pv[r] = f2bfu(fmaxf(acc[f][m][r] + b2v[r], 0.f));
            int byte = (prow << 9) + ((wn * 128 + f * 16 + kg * 4) << 1);
            byte ^= (prow & 7) << 4;
            *(u16x4*)((char*)smem + byte) = pv;
        }
    }
    __syncthreads();

    // ---- GEMM2: h3^T = w3 x h2^T ----
#pragma unroll
    for (int f = 0; f < 8; ++f)
#pragma unroll
        for (int m = 0; m < 2; ++m) acc[f][m] = f32x4{0.f, 0.f, 0.f, 0.f};
    {
        const u16* wp = w3t + ((wn * 128 + l15) << 8);
        GEMM_PIPE(wp)
    }

    // ---- masked col-sum + wave reduce + direct store to part ----
    float s[8][4] = {};
#pragma unroll
    for (int m = 0; m < 2; ++m) {
        int pr = wm * 32 + m * 16 + l15;
        int ki = k0 + (pr >> 3);
        int li = l0 + (pr & 7);
        float vm = (ki < kHW && li < kHW) ? 1.f : 0.f;
#pragma unroll
        for (int f = 0; f < 8; ++f) {
            f32x4 b3v = *(const f32x4*)(b3 + wn * 128 + f * 16 + kg * 4);
#pragma unroll
            for (int r = 0; r < 4; ++r)
                s[f][r] += vm * fmaxf(acc[f][m][r] + b3v[r], 0.f);
        }
    }
#pragma unroll
    for (int f = 0; f < 8; ++f)
#pragma unroll
        for (int r = 0; r < 4; ++r) {
            s[f][r] += __shfl_xor(s[f][r], 1);
            s[f][r] += __shfl_xor(s[f][r], 2);
            s[f][r] += __shfl_xor(s[f][r], 4);
            s[f][r] += __shfl_xor(s[f][r], 8);
        }
    // two pair-half waves (wm 0/1) both hold partials for same channels: store
    // separately into LDS-free path: accumulate via part with wm offset chunks?
    // Simpler: wm=0 stores to psm via LDS then wm=1 adds -> use small LDS region
    __syncthreads();
    float* psm = (float*)smem;
    if (l15 == 0 && wm == 0) {
#pragma unroll
        for (int f = 0; f < 8; ++f)
            *(f32x4*)(psm + wn * 128 + f * 16 + kg * 4) =
                f32x4{s[f][0], s[f][1], s[f][2], s[f][3]};
    }
    __syncthreads();
    if (l15 == 0 && wm == 1) {
        int chunkid = (b * kKC + kc) * kLC + lc;
        float* pp = part + chunkid * 256 + wn * 128 + kg * 4;
        const float* q = psm + wn * 128 + kg * 4;
#pragma unroll
        for (int f = 0; f < 8; ++f) {
            f32x4 prev = *(const f32x4*)(q + f * 16);
            *(f32x4*)(pp + f * 16) = f32x4{s[f][0] + prev[0], s[f][1] + prev[1],
                                           s[f][2] + prev[2], s[f][3] + prev[3]};
        }
    }
}

// ---------------- final reduce over 625 chunks per batch ----------------
__global__ __launch_bounds__(1024)
void k_reduce(const float* __restrict__ part, float* __restrict__ out) {
    __shared__ float red[4][256];
    int b = blockIdx.x;
    int c = threadIdx.x & 255;
    int stripe = threadIdx.x >> 8;
    const float* p = part + (b * kChunks) * 256 + c;
    float s = 0.f;
    for (int j = stripe; j < kChunks; j += 4) s += p[j * 256];
    red[stripe][c] = s;
    __syncthreads();
    if (threadIdx.x < 256)
        out[b * 256 + threadIdx.x] = red[0][threadIdx.x] + red[1][threadIdx.x] +
                                     red[2][threadIdx.x] + red[3][threadIdx.x];
}

extern "C" void kernel_launch(void* const* d_in, const int* in_sizes, int n_in,
                              void* d_out, int out_size, void* d_ws, size_t ws_size,
                              hipStream_t stream) {
    const float* im = (const float*)d_in[0];
    const float* pw = (const float*)d_in[3];
    const float* pb = (const float*)d_in[4];
    const float* w1 = (const float*)d_in[5];
    const float* b1 = (const float*)d_in[6];
    const float* w2 = (const float*)d_in[7];
    const float* b2 = (const float*)d_in[8];
    const float* w3 = (const float*)d_in[9];
    const float* b3 = (const float*)d_in[10];
    float* out = (float*)d_out;

    float* al  = (float*)d_ws;            // 8*196*256
    float* ak  = al + 8 * 196 * 256;
    float* pwT = ak + 8 * 196 * 256;      // [512][256]
    u16* w2t = (u16*)(pwT + 512 * 256);   // [256][256] bf16, [n][k]
    u16* w3t = w2t + 256 * 256;
    float* part = (float*)(w3t + 256 * 256);  // [8*625][256] = 5.12 MB

    hipLaunchKernelGGL(k_tr_f32, dim3(8, 4), dim3(256), 0, stream, pw, pwT, 256, 512);
    hipLaunchKernelGGL(k_tr_bf16, dim3(4, 4), dim3(256), 0, stream, w2, w2t, 256, 256);
    hipLaunchKernelGGL(k_tr_bf16, dim3(4, 4), dim3(256), 0, stream, w3, w3t, 256, 256);
    hipLaunchKernelGGL(k_xa, dim3(25, 8), dim3(512), 0, stream, im, pwT, pb, w1, al, ak);
    hipLaunchKernelGGL(k_main4, dim3(kLC, kKC, 8), dim3(256), 0, stream,
                       ak, al, b1, w2t, b2, w3t, b3, part);
    hipLaunchKernelGGL(k_reduce, dim3(8), dim3(1024), 0, stream, part, out);
}